// Round 1
// baseline (633.312 us; speedup 1.0000x reference)
//
#include <hip/hip_runtime.h>
#include <hip/hip_bf16.h>
#include <cstdint>
#include <cstddef>

#define DIME 2048
#define NH 32
#define NKV 8
#define HD 64
#define BB 2
#define SSEQ 2048
#define PACKED (DIME + 2*NKV*HD)   // 3072
#define MTOT (BB*SSEQ)             // 4096

typedef __attribute__((ext_vector_type(8))) short bf16x8;
typedef __attribute__((ext_vector_type(4))) float f32x4;

__device__ __forceinline__ short f2b(float f) {
  unsigned u = __builtin_bit_cast(unsigned, f);
  u += 0x7fffu + ((u >> 16) & 1u);
  return (short)(u >> 16);
}
__device__ __forceinline__ float b2f(short s) {
  unsigned u = ((unsigned)(unsigned short)s) << 16;
  return __builtin_bit_cast(float, u);
}

__device__ __forceinline__ void gload_lds16(const void* g, void* l) {
  __builtin_amdgcn_global_load_lds(
      (const __attribute__((address_space(1))) void*)g,
      (__attribute__((address_space(3))) void*)l, 16, 0, 0);
}

// ---------------- cast fp32 -> bf16 (vectorized) ----------------
__global__ __launch_bounds__(256) void cast_bf16(const float* __restrict__ in,
                                                 short* __restrict__ out, int n4) {
  int i = blockIdx.x * blockDim.x + threadIdx.x;
  int stride = gridDim.x * blockDim.x;
  for (; i < n4; i += stride) {
    float4 v = ((const float4*)in)[i];
    short4 o;
    o.x = f2b(v.x); o.y = f2b(v.y); o.z = f2b(v.z); o.w = f2b(v.w);
    ((short4*)out)[i] = o;
  }
}

// ---------------- transpose + cast: in fp32 [R][C] -> out bf16 [C][R] ----------------
__global__ __launch_bounds__(256) void transpose_cast(const float* __restrict__ in,
                                                      short* __restrict__ out,
                                                      int R, int C) {
  __shared__ float tile[32][33];
  int bx = blockIdx.x * 32;  // col base in input
  int by = blockIdx.y * 32;  // row base in input
  int tx = threadIdx.x;      // 0..31
  int ty = threadIdx.y;      // 0..7
  #pragma unroll
  for (int j = 0; j < 4; ++j)
    tile[ty + j*8][tx] = in[(size_t)(by + ty + j*8) * C + bx + tx];
  __syncthreads();
  #pragma unroll
  for (int j = 0; j < 4; ++j)
    out[(size_t)(bx + ty + j*8) * R + by + tx] = f2b(tile[tx][ty + j*8]);
}

// ---------------- RoPE cos/sin table: [S][32] ----------------
__global__ __launch_bounds__(256) void rope_table(float* __restrict__ ctab,
                                                  float* __restrict__ stab) {
  int t = blockIdx.x * blockDim.x + threadIdx.x;  // 0..S*32-1
  int s = t >> 5, i = t & 31;
  float theta = 1.0f / powf(10000.0f, (float)(2 * i) * (1.0f / (float)HD));
  float ang = (float)s * theta;
  float sn, cs;
  sincosf(ang, &sn, &cs);
  ctab[t] = cs;
  stab[t] = sn;
}

// ---------------- GEMM: A[M][K] bf16, BT[N][K] bf16 -> C[M][N] ----------------
// m97 structure: 128x128 tile, BK=32, 4 waves (2x2), global_load_lds width 16.
template<bool BF16_OUT>
__global__ __launch_bounds__(256) void gemm_bt(const short* __restrict__ A,
                                               const short* __restrict__ BT,
                                               void* __restrict__ Cout,
                                               int M, int N, int K) {
  __shared__ __align__(16) short As[128 * 32];
  __shared__ __align__(16) short Bs[128 * 32];
  const int tid = threadIdx.x;
  const int l = tid & 63, w = tid >> 6;
  const int lr = l & 15, lg = l >> 4;
  const int wm = w >> 1, wn = w & 1;
  const int bm = blockIdx.x * 128, bn = blockIdx.y * 128;

  f32x4 acc[4][4];
  #pragma unroll
  for (int m = 0; m < 4; ++m)
    #pragma unroll
    for (int n = 0; n < 4; ++n) {
      f32x4 z = {0.f, 0.f, 0.f, 0.f};
      acc[m][n] = z;
    }

  for (int k0 = 0; k0 < K; k0 += 32) {
    #pragma unroll
    for (int c = 0; c < 2; ++c) {
      const int cb = c * 256 + w * 64;       // wave-uniform chunk base
      const int chunk = cb + l;
      const int row = chunk >> 2, col = (chunk & 3) * 8;
      gload_lds16(A  + (size_t)(bm + row) * K + k0 + col, As + cb * 8);
      gload_lds16(BT + (size_t)(bn + row) * K + k0 + col, Bs + cb * 8);
    }
    __syncthreads();
    bf16x8 af[4], bf[4];
    #pragma unroll
    for (int m = 0; m < 4; ++m)
      af[m] = *(const bf16x8*)&As[(wm * 64 + m * 16 + lr) * 32 + lg * 8];
    #pragma unroll
    for (int n = 0; n < 4; ++n)
      bf[n] = *(const bf16x8*)&Bs[(wn * 64 + n * 16 + lr) * 32 + lg * 8];
    #pragma unroll
    for (int m = 0; m < 4; ++m)
      #pragma unroll
      for (int n = 0; n < 4; ++n)
        acc[m][n] = __builtin_amdgcn_mfma_f32_16x16x32_bf16(af[m], bf[n], acc[m][n], 0, 0, 0);
    __syncthreads();
  }

  #pragma unroll
  for (int m = 0; m < 4; ++m)
    #pragma unroll
    for (int n = 0; n < 4; ++n)
      #pragma unroll
      for (int r = 0; r < 4; ++r) {
        int row = bm + wm * 64 + m * 16 + lg * 4 + r;
        int col = bn + wn * 64 + n * 16 + lr;
        if (BF16_OUT)
          ((short*)Cout)[(size_t)row * N + col] = f2b(acc[m][n][r]);
        else
          ((float*)Cout)[(size_t)row * N + col] = acc[m][n][r];
      }
}

// ---------------- RoPE + split qkv -> Q [b][h][s][64], K [b][kvh][s][64] ----------------
__global__ __launch_bounds__(256) void rope_split(const short* __restrict__ qkv,
                                                  const float* __restrict__ ctab,
                                                  const float* __restrict__ stab,
                                                  short* __restrict__ Qo,
                                                  short* __restrict__ Ko) {
  int w = threadIdx.x >> 6, l = threadIdx.x & 63;
  int job = blockIdx.x * 4 + w;          // 0 .. B*S*40-1
  int b = job / (SSEQ * 40);
  int rem = job % (SSEQ * 40);
  int s = rem / 40;
  int hh = rem % 40;                     // 0..31 q heads, 32..39 k heads
  size_t base = (size_t)(b * SSEQ + s) * PACKED;
  int off = (hh < 32) ? (hh * HD + l) : (DIME + (hh - 32) * HD + l);
  float x = b2f(qkv[base + off]);
  float other = __shfl_xor(x, 1);
  int i = l >> 1;
  float cs = ctab[s * 32 + i], sn = stab[s * 32 + i];
  float o = (l & 1) ? (x * cs + other * sn) : (x * cs - other * sn);
  short ob = f2b(o);
  if (hh < 32)
    Qo[((size_t)(b * NH + hh) * SSEQ + s) * HD + l] = ob;
  else
    Ko[((size_t)(b * NKV + (hh - 32)) * SSEQ + s) * HD + l] = ob;
}

// ---------------- V transpose: qkv v-slice [s][64] -> VT [b][kvh][64][S] ----------------
__global__ __launch_bounds__(256) void v_transpose(const short* __restrict__ qkv,
                                                   short* __restrict__ VT) {
  __shared__ __align__(16) short tile[64][72];
  int bkv = blockIdx.x >> 5;            // b*8+kvh
  int st = blockIdx.x & 31;
  int s0 = st * 64;
  int t = threadIdx.x;
  int srow = t >> 2, dq = (t & 3) * 16;
  size_t rowbase = (size_t)((bkv >> 3) * SSEQ + s0 + srow) * PACKED
                   + (DIME + NKV * HD) + (bkv & 7) * HD + dq;
  bf16x8 v0 = *(const bf16x8*)&qkv[rowbase];
  bf16x8 v1 = *(const bf16x8*)&qkv[rowbase + 8];
  #pragma unroll
  for (int j = 0; j < 8; ++j) tile[dq + j][srow] = v0[j];
  #pragma unroll
  for (int j = 0; j < 8; ++j) tile[dq + 8 + j][srow] = v1[j];
  __syncthreads();
  int d = t >> 2, sq = (t & 3) * 16;
  size_t obase = ((size_t)bkv * HD + d) * SSEQ + s0 + sq;
  *(bf16x8*)&VT[obase]     = *(const bf16x8*)&tile[d][sq];
  *(bf16x8*)&VT[obase + 8] = *(const bf16x8*)&tile[d][sq + 8];
}

// ---------------- Flash attention: causal GQA ----------------
// grid (S/64, B*NH). 4 waves x 16 q-rows. KV tile 64. VT is [d][S] so PV's
// B-fragment is contiguous. P goes through per-wave LDS to reach A-layout.
__global__ __launch_bounds__(256) void attn_fwd(const short* __restrict__ Q,
                                                const short* __restrict__ K,
                                                const short* __restrict__ VT,
                                                short* __restrict__ Aout) {
  __shared__ __align__(16) short Plds[4][16 * 64];
  const int qt = blockIdx.x, bh = blockIdx.y;
  const int b = bh >> 5, h = bh & 31, kvh = h >> 2;
  const int tid = threadIdx.x, l = tid & 63, w = tid >> 6;
  const int lr = l & 15, lg = l >> 4;
  const short* Qp = Q + ((size_t)(b * NH + h) * SSEQ) * HD;
  const short* Kp = K + ((size_t)(b * NKV + kvh) * SSEQ) * HD;
  const short* Vp = VT + ((size_t)(b * NKV + kvh) * HD) * SSEQ;
  const int q0 = qt * 64 + w * 16;

  bf16x8 qf0 = *(const bf16x8*)&Qp[(size_t)(q0 + lr) * HD + lg * 8];
  bf16x8 qf1 = *(const bf16x8*)&Qp[(size_t)(q0 + lr) * HD + 32 + lg * 8];

  f32x4 O[4];
  #pragma unroll
  for (int d = 0; d < 4; ++d) { f32x4 z = {0.f,0.f,0.f,0.f}; O[d] = z; }
  float mrun[4], lrun[4];
  #pragma unroll
  for (int r = 0; r < 4; ++r) { mrun[r] = -1e30f; lrun[r] = 0.f; }

  for (int kvt = 0; kvt <= qt; ++kvt) {
    const int kv0 = kvt * 64;
    f32x4 sacc[4];
    #pragma unroll
    for (int kc = 0; kc < 4; ++kc) { f32x4 z = {0.f,0.f,0.f,0.f}; sacc[kc] = z; }
    #pragma unroll
    for (int kc = 0; kc < 4; ++kc) {
      const short* kb = &Kp[(size_t)(kv0 + kc * 16 + lr) * HD + lg * 8];
      bf16x8 kf0 = *(const bf16x8*)kb;
      bf16x8 kf1 = *(const bf16x8*)(kb + 32);
      sacc[kc] = __builtin_amdgcn_mfma_f32_16x16x32_bf16(qf0, kf0, sacc[kc], 0, 0, 0);
      sacc[kc] = __builtin_amdgcn_mfma_f32_16x16x32_bf16(qf1, kf1, sacc[kc], 0, 0, 0);
    }
    // scale + causal mask + online softmax.  C-layout: row=lg*4+r (q), col=lr (kv)
    float p[4][4], rmax[4];
    #pragma unroll
    for (int r = 0; r < 4; ++r) rmax[r] = -1e30f;
    const bool diag = (kvt == qt);
    #pragma unroll
    for (int kc = 0; kc < 4; ++kc)
      #pragma unroll
      for (int r = 0; r < 4; ++r) {
        float v = sacc[kc][r] * 0.125f;
        if (diag && (kv0 + kc * 16 + lr) > (q0 + lg * 4 + r)) v = -1e30f;
        p[kc][r] = v;
        rmax[r] = fmaxf(rmax[r], v);
      }
    #pragma unroll
    for (int off = 1; off < 16; off <<= 1)
      #pragma unroll
      for (int r = 0; r < 4; ++r) rmax[r] = fmaxf(rmax[r], __shfl_xor(rmax[r], off));
    float corr[4], rsum[4];
    #pragma unroll
    for (int r = 0; r < 4; ++r) {
      float mn = fmaxf(mrun[r], rmax[r]);
      corr[r] = __expf(mrun[r] - mn);
      mrun[r] = mn;
      rsum[r] = 0.f;
    }
    #pragma unroll
    for (int kc = 0; kc < 4; ++kc)
      #pragma unroll
      for (int r = 0; r < 4; ++r) {
        float e = __expf(p[kc][r] - mrun[r]);
        p[kc][r] = e;
        rsum[r] += e;
      }
    #pragma unroll
    for (int off = 1; off < 16; off <<= 1)
      #pragma unroll
      for (int r = 0; r < 4; ++r) rsum[r] += __shfl_xor(rsum[r], off);
    #pragma unroll
    for (int r = 0; r < 4; ++r) lrun[r] = lrun[r] * corr[r] + rsum[r];
    #pragma unroll
    for (int d = 0; d < 4; ++d)
      #pragma unroll
      for (int r = 0; r < 4; ++r) O[d][r] *= corr[r];
    // P -> LDS (row-major [16 q][64 kv]) -> A-fragments
    #pragma unroll
    for (int kc = 0; kc < 4; ++kc)
      #pragma unroll
      for (int r = 0; r < 4; ++r)
        Plds[w][(lg * 4 + r) * 64 + kc * 16 + lr] = f2b(p[kc][r]);
    __syncthreads();
    bf16x8 pf0 = *(const bf16x8*)&Plds[w][lr * 64 + lg * 8];
    bf16x8 pf1 = *(const bf16x8*)&Plds[w][lr * 64 + 32 + lg * 8];
    #pragma unroll
    for (int d = 0; d < 4; ++d) {
      const short* vb = &Vp[(size_t)(d * 16 + lr) * SSEQ + kv0 + lg * 8];
      bf16x8 vf0 = *(const bf16x8*)vb;
      bf16x8 vf1 = *(const bf16x8*)(vb + 32);
      O[d] = __builtin_amdgcn_mfma_f32_16x16x32_bf16(pf0, vf0, O[d], 0, 0, 0);
      O[d] = __builtin_amdgcn_mfma_f32_16x16x32_bf16(pf1, vf1, O[d], 0, 0, 0);
    }
    __syncthreads();
  }
  #pragma unroll
  for (int d = 0; d < 4; ++d)
    #pragma unroll
    for (int r = 0; r < 4; ++r) {
      float o = O[d][r] / lrun[r];
      int qpos = q0 + lg * 4 + r;
      Aout[(size_t)(b * SSEQ + qpos) * DIME + h * HD + d * 16 + lr] = f2b(o);
    }
}

extern "C" void kernel_launch(void* const* d_in, const int* in_sizes, int n_in,
                              void* d_out, int out_size, void* d_ws, size_t ws_size,
                              hipStream_t stream) {
  const float* x     = (const float*)d_in[0];
  const float* w_qkv = (const float*)d_in[1];
  const float* w_out = (const float*)d_in[2];
  float* out = (float*)d_out;

  char* ws = (char*)d_ws;
  size_t off = 0;
  auto alloc = [&](size_t bytes) -> void* {
    void* p = ws + off;
    off += (bytes + 255) & ~(size_t)255;
    return p;
  };
  short* xb    = (short*)alloc((size_t)MTOT * DIME * 2);
  short* wqkvT = (short*)alloc((size_t)PACKED * DIME * 2);
  short* woutT = (short*)alloc((size_t)DIME * DIME * 2);
  short* qkv   = (short*)alloc((size_t)MTOT * PACKED * 2);
  short* Qb    = (short*)alloc((size_t)BB * NH * SSEQ * HD * 2);
  short* Kb    = (short*)alloc((size_t)BB * NKV * SSEQ * HD * 2);
  short* VTb   = (short*)alloc((size_t)BB * NKV * HD * SSEQ * 2);
  float* ctab  = (float*)alloc((size_t)SSEQ * 32 * 4);
  float* stab  = (float*)alloc((size_t)SSEQ * 32 * 4);
  short* attnb = qkv;  // reuse: qkv dead after rope_split + v_transpose

  cast_bf16<<<2048, 256, 0, stream>>>(x, xb, MTOT * DIME / 4);
  transpose_cast<<<dim3(PACKED / 32, DIME / 32), dim3(32, 8), 0, stream>>>(w_qkv, wqkvT, DIME, PACKED);
  transpose_cast<<<dim3(DIME / 32, DIME / 32), dim3(32, 8), 0, stream>>>(w_out, woutT, DIME, DIME);
  rope_table<<<(SSEQ * 32) / 256, 256, 0, stream>>>(ctab, stab);

  gemm_bt<true><<<dim3(MTOT / 128, PACKED / 128), 256, 0, stream>>>(xb, wqkvT, qkv, MTOT, PACKED, DIME);

  rope_split<<<(BB * SSEQ * 40) / 4, 256, 0, stream>>>(qkv, ctab, stab, Qb, Kb);
  v_transpose<<<BB * NKV * (SSEQ / 64), 256, 0, stream>>>(qkv, VTb);

  attn_fwd<<<dim3(SSEQ / 64, BB * NH), 256, 0, stream>>>(Qb, Kb, VTb, attnb);

  gemm_bt<false><<<dim3(MTOT / 128, DIME / 128), 256, 0, stream>>>(attnb, woutT, out, MTOT, DIME, DIME);
}

// Round 2
// 302.031 us; speedup vs baseline: 2.0968x; 2.0968x over previous
//
#include <hip/hip_runtime.h>
#include <hip/hip_bf16.h>
#include <cstdint>
#include <cstddef>

#define DIME 2048
#define NH 32
#define NKV 8
#define HD 64
#define BB 2
#define SSEQ 2048
#define PACKED (DIME + 2*NKV*HD)   // 3072
#define MTOT (BB*SSEQ)             // 4096

typedef __attribute__((ext_vector_type(8))) short bf16x8;
typedef __attribute__((ext_vector_type(4))) float f32x4;

__device__ __forceinline__ short f2b(float f) {
  unsigned u = __builtin_bit_cast(unsigned, f);
  u += 0x7fffu + ((u >> 16) & 1u);
  return (short)(u >> 16);
}
__device__ __forceinline__ float b2f(short s) {
  unsigned u = ((unsigned)(unsigned short)s) << 16;
  return __builtin_bit_cast(float, u);
}

__device__ __forceinline__ void gload_lds16(const void* g, void* l) {
  __builtin_amdgcn_global_load_lds(
      (const __attribute__((address_space(1))) void*)g,
      (__attribute__((address_space(3))) void*)l, 16, 0, 0);
}

// ---------------- cast fp32 -> bf16 (vectorized) ----------------
__global__ __launch_bounds__(256) void cast_bf16(const float* __restrict__ in,
                                                 short* __restrict__ out, int n4) {
  int i = blockIdx.x * blockDim.x + threadIdx.x;
  int stride = gridDim.x * blockDim.x;
  for (; i < n4; i += stride) {
    float4 v = ((const float4*)in)[i];
    short4 o;
    o.x = f2b(v.x); o.y = f2b(v.y); o.z = f2b(v.z); o.w = f2b(v.w);
    ((short4*)out)[i] = o;
  }
}

// ---------------- transpose + cast: in fp32 [R][C] -> out bf16 [C][R] ----------------
__global__ __launch_bounds__(256) void transpose_cast(const float* __restrict__ in,
                                                      short* __restrict__ out,
                                                      int R, int C) {
  __shared__ float tile[32][33];
  int bx = blockIdx.x * 32;
  int by = blockIdx.y * 32;
  int tx = threadIdx.x;
  int ty = threadIdx.y;
  #pragma unroll
  for (int j = 0; j < 4; ++j)
    tile[ty + j*8][tx] = in[(size_t)(by + ty + j*8) * C + bx + tx];
  __syncthreads();
  #pragma unroll
  for (int j = 0; j < 4; ++j)
    out[(size_t)(bx + ty + j*8) * R + by + tx] = f2b(tile[tx][ty + j*8]);
}

// ---------------- RoPE cos/sin table: [S][32] ----------------
__global__ __launch_bounds__(256) void rope_table(float* __restrict__ ctab,
                                                  float* __restrict__ stab) {
  int t = blockIdx.x * blockDim.x + threadIdx.x;
  int s = t >> 5, i = t & 31;
  float theta = 1.0f / powf(10000.0f, (float)(2 * i) * (1.0f / (float)HD));
  float ang = (float)s * theta;
  float sn, cs;
  sincosf(ang, &sn, &cs);
  ctab[t] = cs;
  stab[t] = sn;
}

// ---------------- GEMM: A[M][K] bf16, BT[N][K] bf16 -> C[M][N] ----------------
template<bool BF16_OUT>
__global__ __launch_bounds__(256) void gemm_bt(const short* __restrict__ A,
                                               const short* __restrict__ BT,
                                               void* __restrict__ Cout,
                                               int M, int N, int K) {
  __shared__ __align__(16) short As[128 * 32];
  __shared__ __align__(16) short Bs[128 * 32];
  const int tid = threadIdx.x;
  const int l = tid & 63, w = tid >> 6;
  const int lr = l & 15, lg = l >> 4;
  const int wm = w >> 1, wn = w & 1;
  const int bm = blockIdx.x * 128, bn = blockIdx.y * 128;

  f32x4 acc[4][4];
  #pragma unroll
  for (int m = 0; m < 4; ++m)
    #pragma unroll
    for (int n = 0; n < 4; ++n) {
      f32x4 z = {0.f, 0.f, 0.f, 0.f};
      acc[m][n] = z;
    }

  for (int k0 = 0; k0 < K; k0 += 32) {
    #pragma unroll
    for (int c = 0; c < 2; ++c) {
      const int cb = c * 256 + w * 64;
      const int chunk = cb + l;
      const int row = chunk >> 2, col = (chunk & 3) * 8;
      gload_lds16(A  + (size_t)(bm + row) * K + k0 + col, As + cb * 8);
      gload_lds16(BT + (size_t)(bn + row) * K + k0 + col, Bs + cb * 8);
    }
    __syncthreads();
    bf16x8 af[4], bf[4];
    #pragma unroll
    for (int m = 0; m < 4; ++m)
      af[m] = *(const bf16x8*)&As[(wm * 64 + m * 16 + lr) * 32 + lg * 8];
    #pragma unroll
    for (int n = 0; n < 4; ++n)
      bf[n] = *(const bf16x8*)&Bs[(wn * 64 + n * 16 + lr) * 32 + lg * 8];
    #pragma unroll
    for (int m = 0; m < 4; ++m)
      #pragma unroll
      for (int n = 0; n < 4; ++n)
        acc[m][n] = __builtin_amdgcn_mfma_f32_16x16x32_bf16(af[m], bf[n], acc[m][n], 0, 0, 0);
    __syncthreads();
  }

  #pragma unroll
  for (int m = 0; m < 4; ++m)
    #pragma unroll
    for (int n = 0; n < 4; ++n)
      #pragma unroll
      for (int r = 0; r < 4; ++r) {
        int row = bm + wm * 64 + m * 16 + lg * 4 + r;
        int col = bn + wn * 64 + n * 16 + lr;
        if (BF16_OUT)
          ((short*)Cout)[(size_t)row * N + col] = f2b(acc[m][n][r]);
        else
          ((float*)Cout)[(size_t)row * N + col] = acc[m][n][r];
      }
}

// ---------------- RoPE + split qkv -> Q [b][h][s][64], K [b][kvh][s][64] ----------------
__global__ __launch_bounds__(256) void rope_split(const short* __restrict__ qkv,
                                                  const float* __restrict__ ctab,
                                                  const float* __restrict__ stab,
                                                  short* __restrict__ Qo,
                                                  short* __restrict__ Ko) {
  int w = threadIdx.x >> 6, l = threadIdx.x & 63;
  int job = blockIdx.x * 4 + w;
  int b = job / (SSEQ * 40);
  int rem = job % (SSEQ * 40);
  int s = rem / 40;
  int hh = rem % 40;
  size_t base = (size_t)(b * SSEQ + s) * PACKED;
  int off = (hh < 32) ? (hh * HD + l) : (DIME + (hh - 32) * HD + l);
  float x = b2f(qkv[base + off]);
  float other = __shfl_xor(x, 1);
  int i = l >> 1;
  float cs = ctab[s * 32 + i], sn = stab[s * 32 + i];
  float o = (l & 1) ? (x * cs + other * sn) : (x * cs - other * sn);
  short ob = f2b(o);
  if (hh < 32)
    Qo[((size_t)(b * NH + hh) * SSEQ + s) * HD + l] = ob;
  else
    Ko[((size_t)(b * NKV + (hh - 32)) * SSEQ + s) * HD + l] = ob;
}

// ---------------- V transpose: qkv v-slice [s][64] -> VT [b][kvh][64][S] ----------------
__global__ __launch_bounds__(256) void v_transpose(const short* __restrict__ qkv,
                                                   short* __restrict__ VT) {
  __shared__ __align__(16) short tile[64][72];
  int bkv = blockIdx.x >> 5;
  int st = blockIdx.x & 31;
  int s0 = st * 64;
  int t = threadIdx.x;
  int srow = t >> 2, dq = (t & 3) * 16;
  size_t rowbase = (size_t)((bkv >> 3) * SSEQ + s0 + srow) * PACKED
                   + (DIME + NKV * HD) + (bkv & 7) * HD + dq;
  bf16x8 v0 = *(const bf16x8*)&qkv[rowbase];
  bf16x8 v1 = *(const bf16x8*)&qkv[rowbase + 8];
  #pragma unroll
  for (int j = 0; j < 8; ++j) tile[dq + j][srow] = v0[j];
  #pragma unroll
  for (int j = 0; j < 8; ++j) tile[dq + 8 + j][srow] = v1[j];
  __syncthreads();
  int d = t >> 2, sq = (t & 3) * 16;
  size_t obase = ((size_t)bkv * HD + d) * SSEQ + s0 + sq;
  *(bf16x8*)&VT[obase]     = *(const bf16x8*)&tile[d][sq];
  *(bf16x8*)&VT[obase + 8] = *(const bf16x8*)&tile[d][sq + 8];
}

// ---------------- Flash attention: causal GQA, v2 ----------------
// 4 independent waves per block (no block barriers). Each wave owns QBLK=32
// q-rows and processes TWO chunks (c, 63-c) for uniform causal work.
// P goes through a per-wave XOR-swizzled LDS buffer (T2: byte ^= (row&7)<<4).
// Deferred l-sum: per-lane partials, one cross-lane reduce at the end.
__global__ __launch_bounds__(256) void attn_fwd(const short* __restrict__ Q,
                                                const short* __restrict__ K,
                                                const short* __restrict__ VT,
                                                short* __restrict__ Aout) {
  __shared__ __align__(16) short Plds[4][32 * 64];
  const int tid = threadIdx.x, l = tid & 63, w = tid >> 6;
  const int lr = l & 15, lg = l >> 4;
  const int job = blockIdx.x * 4 + w;      // 0..2047
  const int bh = job >> 5;                 // 0..63
  const int cpair = job & 31;              // 0..31
  const int b = bh >> 5, h = bh & 31, kvh = h >> 2;
  const short* Qp = Q + (size_t)(b * NH + h) * SSEQ * HD;
  const short* Kp = K + (size_t)(b * NKV + kvh) * SSEQ * HD;
  const short* Vp = VT + (size_t)(b * NKV + kvh) * HD * SSEQ;
  short* Pw = (short*)Plds[w];

  #pragma unroll
  for (int half = 0; half < 2; ++half) {
    const int c = half ? (63 - cpair) : cpair;
    const int q0 = c * 32;

    bf16x8 qf[2][2];
    #pragma unroll
    for (int m = 0; m < 2; ++m)
      #pragma unroll
      for (int kh = 0; kh < 2; ++kh)
        qf[m][kh] = *(const bf16x8*)&Qp[(size_t)(q0 + m * 16 + lr) * HD + kh * 32 + lg * 8];

    f32x4 O[2][4];
    #pragma unroll
    for (int m = 0; m < 2; ++m)
      #pragma unroll
      for (int d = 0; d < 4; ++d) { f32x4 z = {0.f,0.f,0.f,0.f}; O[m][d] = z; }
    float mrun[2][4], lpart[2][4];
    #pragma unroll
    for (int m = 0; m < 2; ++m)
      #pragma unroll
      for (int r = 0; r < 4; ++r) { mrun[m][r] = -3e38f; lpart[m][r] = 0.f; }

    const int nkvt = (c >> 1) + 1;
    for (int kvt = 0; kvt < nkvt; ++kvt) {
      const int kv0 = kvt * 64;
      // --- QK^T ---
      bf16x8 kf[4][2];
      #pragma unroll
      for (int n = 0; n < 4; ++n)
        #pragma unroll
        for (int kh = 0; kh < 2; ++kh)
          kf[n][kh] = *(const bf16x8*)&Kp[(size_t)(kv0 + n * 16 + lr) * HD + kh * 32 + lg * 8];
      f32x4 sacc[2][4];
      #pragma unroll
      for (int m = 0; m < 2; ++m)
        #pragma unroll
        for (int n = 0; n < 4; ++n) { f32x4 z = {0.f,0.f,0.f,0.f}; sacc[m][n] = z; }
      #pragma unroll
      for (int m = 0; m < 2; ++m)
        #pragma unroll
        for (int n = 0; n < 4; ++n) {
          sacc[m][n] = __builtin_amdgcn_mfma_f32_16x16x32_bf16(qf[m][0], kf[n][0], sacc[m][n], 0, 0, 0);
          sacc[m][n] = __builtin_amdgcn_mfma_f32_16x16x32_bf16(qf[m][1], kf[n][1], sacc[m][n], 0, 0, 0);
        }
      // --- softmax (online, deferred l-sum) ---
      const bool diag = (kvt == nkvt - 1);
      float p[2][4][4], rmax[2][4];
      #pragma unroll
      for (int m = 0; m < 2; ++m)
        #pragma unroll
        for (int r = 0; r < 4; ++r) rmax[m][r] = -3e38f;
      #pragma unroll
      for (int m = 0; m < 2; ++m)
        #pragma unroll
        for (int n = 0; n < 4; ++n)
          #pragma unroll
          for (int r = 0; r < 4; ++r) {
            float v = sacc[m][n][r] * 0.125f;
            if (diag && (kv0 + n * 16 + lr) > (q0 + m * 16 + lg * 4 + r)) v = -3e38f;
            p[m][n][r] = v;
            rmax[m][r] = fmaxf(rmax[m][r], v);
          }
      #pragma unroll
      for (int off = 1; off < 16; off <<= 1)
        #pragma unroll
        for (int m = 0; m < 2; ++m)
          #pragma unroll
          for (int r = 0; r < 4; ++r)
            rmax[m][r] = fmaxf(rmax[m][r], __shfl_xor(rmax[m][r], off));
      float corr[2][4];
      #pragma unroll
      for (int m = 0; m < 2; ++m)
        #pragma unroll
        for (int r = 0; r < 4; ++r) {
          float mn = fmaxf(mrun[m][r], rmax[m][r]);
          corr[m][r] = __expf(mrun[m][r] - mn);
          mrun[m][r] = mn;
        }
      #pragma unroll
      for (int m = 0; m < 2; ++m)
        #pragma unroll
        for (int r = 0; r < 4; ++r) {
          float ls = 0.f;
          #pragma unroll
          for (int n = 0; n < 4; ++n) {
            float e = __expf(p[m][n][r] - mrun[m][r]);
            p[m][n][r] = e;
            ls += e;
          }
          lpart[m][r] = lpart[m][r] * corr[m][r] + ls;
        }
      // --- P -> swizzled LDS ---
      #pragma unroll
      for (int m = 0; m < 2; ++m)
        #pragma unroll
        for (int n = 0; n < 4; ++n)
          #pragma unroll
          for (int r = 0; r < 4; ++r) {
            int row = m * 16 + lg * 4 + r;
            int byte = (row * 64 + n * 16 + lr) * 2;
            byte ^= (row & 7) << 4;
            Pw[byte >> 1] = f2b(p[m][n][r]);
          }
      // --- O rescale ---
      #pragma unroll
      for (int m = 0; m < 2; ++m)
        #pragma unroll
        for (int d = 0; d < 4; ++d)
          #pragma unroll
          for (int r = 0; r < 4; ++r) O[m][d][r] *= corr[m][r];
      // --- PV ---
      bf16x8 pf[2][2];
      #pragma unroll
      for (int m = 0; m < 2; ++m)
        #pragma unroll
        for (int kh = 0; kh < 2; ++kh) {
          int byte = ((m * 16 + lr) * 64 + kh * 32 + lg * 8) * 2;
          byte ^= (lr & 7) << 4;
          pf[m][kh] = *(const bf16x8*)&Pw[byte >> 1];
        }
      bf16x8 vf[4][2];
      #pragma unroll
      for (int d = 0; d < 4; ++d)
        #pragma unroll
        for (int kh = 0; kh < 2; ++kh)
          vf[d][kh] = *(const bf16x8*)&Vp[(size_t)(d * 16 + lr) * SSEQ + kv0 + kh * 32 + lg * 8];
      #pragma unroll
      for (int m = 0; m < 2; ++m)
        #pragma unroll
        for (int d = 0; d < 4; ++d) {
          O[m][d] = __builtin_amdgcn_mfma_f32_16x16x32_bf16(pf[m][0], vf[d][0], O[m][d], 0, 0, 0);
          O[m][d] = __builtin_amdgcn_mfma_f32_16x16x32_bf16(pf[m][1], vf[d][1], O[m][d], 0, 0, 0);
        }
    }
    // --- final l reduce + output ---
    #pragma unroll
    for (int off = 1; off < 16; off <<= 1)
      #pragma unroll
      for (int m = 0; m < 2; ++m)
        #pragma unroll
        for (int r = 0; r < 4; ++r)
          lpart[m][r] += __shfl_xor(lpart[m][r], off);
    #pragma unroll
    for (int m = 0; m < 2; ++m)
      #pragma unroll
      for (int r = 0; r < 4; ++r) {
        float inv = 1.0f / lpart[m][r];
        int qpos = q0 + m * 16 + lg * 4 + r;
        #pragma unroll
        for (int d = 0; d < 4; ++d)
          Aout[(size_t)(b * SSEQ + qpos) * DIME + h * HD + d * 16 + lr] = f2b(O[m][d][r] * inv);
      }
  }
}

extern "C" void kernel_launch(void* const* d_in, const int* in_sizes, int n_in,
                              void* d_out, int out_size, void* d_ws, size_t ws_size,
                              hipStream_t stream) {
  const float* x     = (const float*)d_in[0];
  const float* w_qkv = (const float*)d_in[1];
  const float* w_out = (const float*)d_in[2];
  float* out = (float*)d_out;

  char* ws = (char*)d_ws;
  size_t off = 0;
  auto alloc = [&](size_t bytes) -> void* {
    void* p = ws + off;
    off += (bytes + 255) & ~(size_t)255;
    return p;
  };
  short* xb    = (short*)alloc((size_t)MTOT * DIME * 2);
  short* wqkvT = (short*)alloc((size_t)PACKED * DIME * 2);
  short* woutT = (short*)alloc((size_t)DIME * DIME * 2);
  short* qkv   = (short*)alloc((size_t)MTOT * PACKED * 2);
  short* Qb    = (short*)alloc((size_t)BB * NH * SSEQ * HD * 2);
  short* Kb    = (short*)alloc((size_t)BB * NKV * SSEQ * HD * 2);
  short* VTb   = (short*)alloc((size_t)BB * NKV * HD * SSEQ * 2);
  float* ctab  = (float*)alloc((size_t)SSEQ * 32 * 4);
  float* stab  = (float*)alloc((size_t)SSEQ * 32 * 4);
  short* attnb = qkv;  // reuse: qkv dead after rope_split + v_transpose

  cast_bf16<<<2048, 256, 0, stream>>>(x, xb, MTOT * DIME / 4);
  transpose_cast<<<dim3(PACKED / 32, DIME / 32), dim3(32, 8), 0, stream>>>(w_qkv, wqkvT, DIME, PACKED);
  transpose_cast<<<dim3(DIME / 32, DIME / 32), dim3(32, 8), 0, stream>>>(w_out, woutT, DIME, DIME);
  rope_table<<<(SSEQ * 32) / 256, 256, 0, stream>>>(ctab, stab);

  gemm_bt<true><<<dim3(MTOT / 128, PACKED / 128), 256, 0, stream>>>(xb, wqkvT, qkv, MTOT, PACKED, DIME);

  rope_split<<<(BB * SSEQ * 40) / 4, 256, 0, stream>>>(qkv, ctab, stab, Qb, Kb);
  v_transpose<<<BB * NKV * (SSEQ / 64), 256, 0, stream>>>(qkv, VTb);

  attn_fwd<<<512, 256, 0, stream>>>(Qb, Kb, VTb, attnb);

  gemm_bt<false><<<dim3(MTOT / 128, DIME / 128), 256, 0, stream>>>(attnb, woutT, out, MTOT, DIME, DIME);
}